// Round 3
// baseline (579.563 us; speedup 1.0000x reference)
//
#include <hip/hip_runtime.h>
#include <stdint.h>

typedef unsigned long long u64;

#define BATCH 16384
#define FEAT  1024
#define KW    16          // 1024 bits / 64 per row (= 8 uint4 per row)
#define NCLS  10

// ---- workspace layout (bytes) ----
#define OFF_XA   ((size_t)0)
#define OFF_XB   ((size_t)(2u * 1024u * 1024u))
#define OFF_WP1  ((size_t)(4u * 1024u * 1024u))          // 128 KB each
#define OFF_WP2  (OFF_WP1 + (size_t)FEAT * KW * 8)
#define OFF_WP3  (OFF_WP2 + (size_t)FEAT * KW * 8)
#define OFF_WP4  (OFF_WP3 + (size_t)FEAT * KW * 8)       // 160 u64 = 1280 B
#define OFF_TH   (OFF_WP4 + (size_t)2048)                 // 3*1024 int2 = 24 KB

// ---------------------------------------------------------------------------
// Fused prep: pack sign bits of x (thr 0.5) and W1..W4 (thr 0.0), plus the
// per-column BN integer thresholds. Block-uniform branch on blockIdx ranges.
#define NB_X   65536           // 16384*1024/256
#define NB_W   4096            // 1024*1024/256
#define NB_W4  40              // 10*1024/256
#define NB_TH  12              // 3*1024/256

__global__ void __launch_bounds__(256) prep_kernel(
    const float* __restrict__ x,
    const float* __restrict__ W1, const float* __restrict__ W2,
    const float* __restrict__ W3, const float* __restrict__ W4,
    const float* __restrict__ g1, const float* __restrict__ b1,
    const float* __restrict__ m1, const float* __restrict__ v1,
    const float* __restrict__ g2, const float* __restrict__ b2,
    const float* __restrict__ m2, const float* __restrict__ v2,
    const float* __restrict__ g3, const float* __restrict__ b3,
    const float* __restrict__ m3, const float* __restrict__ v3,
    u64* __restrict__ XA, u64* __restrict__ Wp1, u64* __restrict__ Wp2,
    u64* __restrict__ Wp3, u64* __restrict__ Wp4, int2* __restrict__ TH)
{
    int b = blockIdx.x;
    if (b >= NB_X + 3 * NB_W + NB_W4) {
        // BN thresholds: y = (h-m)*s + b >= 0, s = g*rsqrt(v+eps)
        int gid = (b - (NB_X + 3 * NB_W + NB_W4)) * 256 + threadIdx.x; // 0..3071
        int l = gid >> 10, j = gid & 1023;
        const float *g, *bb, *m, *v;
        if (l == 0)      { g = g1; bb = b1; m = m1; v = v1; }
        else if (l == 1) { g = g2; bb = b2; m = m2; v = v2; }
        else             { g = g3; bb = b3; m = m3; v = v3; }
        double gd = (double)g[j], bd = (double)bb[j], md = (double)m[j], vd = (double)v[j];
        double s = gd / sqrt(vd + 1e-5);
        int ti, flip;
        if (s > 0.0)      { ti = (int)ceil(md - bd / s);  flip = 0; }
        else if (s < 0.0) { ti = (int)floor(md - bd / s); flip = 1; }
        else              { ti = (bd >= 0.0) ? -2000000 : 2000000; flip = 0; }
        TH[gid] = make_int2(ti, flip);
        return;
    }
    const float* src; u64* dst; float thr; int base;
    if (b < NB_X)                    { src = x;  dst = XA;  thr = 0.5f; base = b; }
    else if (b < NB_X + NB_W)        { src = W1; dst = Wp1; thr = 0.0f; base = b - NB_X; }
    else if (b < NB_X + 2 * NB_W)    { src = W2; dst = Wp2; thr = 0.0f; base = b - (NB_X + NB_W); }
    else if (b < NB_X + 3 * NB_W)    { src = W3; dst = Wp3; thr = 0.0f; base = b - (NB_X + 2 * NB_W); }
    else                             { src = W4; dst = Wp4; thr = 0.0f; base = b - (NB_X + 3 * NB_W); }
    int i = base * 256 + threadIdx.x;
    bool bit = src[i] >= thr;
    u64 m = __ballot(bit);
    if ((threadIdx.x & 63) == 0) dst[i >> 6] = m;
}

// ---------------------------------------------------------------------------
// Binary GEMM layer. 128x128 tile / 256 threads, 8x8 register tile.
// LDS stored as uint4 pair-slots with slot = q ^ ((row>>3)&7):
//   - staging: aligned b128 writes, banks evenly covered
//   - X reads: 4 distinct addrs/wave (broadcast), W reads: 2-way max (free)
__global__ void __launch_bounds__(256, 4)
gemm_bin_kernel(const uint4* __restrict__ Xin, const uint4* __restrict__ Wp,
                const int2* __restrict__ th, u64* __restrict__ Xout) {
    __shared__ uint4 Xs[128][8];
    __shared__ uint4 Ws[128][8];

    const int tid = threadIdx.x;
    const int bx = blockIdx.x & 7;    // col block
    const int by = blockIdx.x >> 3;   // row block

    const uint4* Xg = Xin + (size_t)by * 128 * 8;   // 16 KB contiguous
    const uint4* Wg = Wp + (size_t)bx * 128 * 8;

#pragma unroll
    for (int i = 0; i < 4; ++i) {
        int idx = tid + i * 256;          // uint4 index 0..1023
        int row = idx >> 3;
        int q = idx & 7;
        int c = (row >> 3) & 7;
        Xs[row][q ^ c] = Xg[idx];
        Ws[row][q ^ c] = Wg[idx];
    }
    __syncthreads();

    const int tr = tid >> 4;    // 0..15 -> rows tr*8..tr*8+7
    const int tc = tid & 15;    // 0..15 -> cols tc*8..tc*8+7
    const int cx = tr & 7;
    const int cw = tc & 7;

    int acc[8][8];
#pragma unroll
    for (int i = 0; i < 8; ++i)
#pragma unroll
        for (int j = 0; j < 8; ++j) acc[i][j] = 0;

#pragma unroll 1
    for (int p = 0; p < 8; ++p) {
        uint4 xw[8];
#pragma unroll
        for (int i = 0; i < 8; ++i) xw[i] = Xs[tr * 8 + i][p ^ cx];
#pragma unroll
        for (int j = 0; j < 8; ++j) {
            uint4 wv = Ws[tc * 8 + j][p ^ cw];
#pragma unroll
            for (int i = 0; i < 8; ++i) {
                acc[i][j] += __popc(xw[i].x ^ wv.x) + __popc(xw[i].y ^ wv.y)
                           + __popc(xw[i].z ^ wv.z) + __popc(xw[i].w ^ wv.w);
            }
        }
    }

    int2 t8[8];
#pragma unroll
    for (int j = 0; j < 8; ++j) t8[j] = th[bx * 128 + tc * 8 + j];

    __syncthreads();
    // Reuse Xs as a 128x16 byte tile: byte (row, tc) = bits for cols tc*8..+7
    unsigned char* Bb = (unsigned char*)&Xs[0][0];
#pragma unroll
    for (int i = 0; i < 8; ++i) {
        unsigned int byte = 0;
#pragma unroll
        for (int j = 0; j < 8; ++j) {
            int h = 1024 - 2 * acc[i][j];
            int bit = t8[j].y ? (h <= t8[j].x) : (h >= t8[j].x);
            byte |= (unsigned int)bit << j;
        }
        Bb[(tr * 8 + i) * 16 + tc] = (unsigned char)byte;
    }
    __syncthreads();

    int lrow = tid >> 1, half = tid & 1;
    u64 word = *(const u64*)&Bb[lrow * 16 + half * 8];
    Xout[(size_t)(by * 128 + lrow) * KW + bx * 2 + half] = word;
}

// ---------------------------------------------------------------------------
// Final 1024 -> 10 binary matmul + TensorNorm. One row per thread, W4 in LDS.
// NOTE: one row of packed bits = 16 u64 = 8 uint4 (R2 bug: used 4, wrong stride).
__global__ void __launch_bounds__(256) final_layer_kernel(
    const uint4* __restrict__ X3, const u64* __restrict__ W4p,
    const float* __restrict__ tw, const float* __restrict__ tb,
    const float* __restrict__ tm, const float* __restrict__ tv,
    float* __restrict__ out) {
    __shared__ u64 Wl[NCLS * KW];   // 160 u64 = 80 uint4
    if (threadIdx.x < NCLS * KW) Wl[threadIdx.x] = W4p[threadIdx.x];
    __syncthreads();

    int row = blockIdx.x * 256 + threadIdx.x;   // 64 blocks -> 16384 rows
    uint4 xr[8];
#pragma unroll
    for (int t = 0; t < 8; ++t) xr[t] = X3[(size_t)row * 8 + t];

    double sc = (double)tw[0] / sqrt((double)tv[0] + 1e-4);
    double off = (double)tb[0] - (double)tm[0] * sc;

    const uint4* Wl4 = (const uint4*)Wl;
#pragma unroll
    for (int c = 0; c < NCLS; ++c) {
        int p = 0;
#pragma unroll
        for (int t = 0; t < 8; ++t) {
            uint4 wv = Wl4[c * 8 + t];
            p += __popc(xr[t].x ^ wv.x) + __popc(xr[t].y ^ wv.y)
               + __popc(xr[t].z ^ wv.z) + __popc(xr[t].w ^ wv.w);
        }
        int h = 1024 - 2 * p;
        out[(size_t)row * NCLS + c] = (float)((double)h * sc + off);
    }
}

// ---------------------------------------------------------------------------
extern "C" void kernel_launch(void* const* d_in, const int* in_sizes, int n_in,
                              void* d_out, int out_size, void* d_ws, size_t ws_size,
                              hipStream_t stream) {
    const float* x  = (const float*)d_in[0];
    const float* W1 = (const float*)d_in[1];
    const float* W2 = (const float*)d_in[2];
    const float* W3 = (const float*)d_in[3];
    const float* W4 = (const float*)d_in[4];
    const float* g1 = (const float*)d_in[5];
    const float* b1 = (const float*)d_in[6];
    const float* m1 = (const float*)d_in[7];
    const float* v1 = (const float*)d_in[8];
    const float* g2 = (const float*)d_in[9];
    const float* b2 = (const float*)d_in[10];
    const float* m2 = (const float*)d_in[11];
    const float* v2 = (const float*)d_in[12];
    const float* g3 = (const float*)d_in[13];
    const float* b3 = (const float*)d_in[14];
    const float* m3 = (const float*)d_in[15];
    const float* v3 = (const float*)d_in[16];
    const float* tw = (const float*)d_in[17];
    const float* tb = (const float*)d_in[18];
    const float* tm = (const float*)d_in[19];
    const float* tv = (const float*)d_in[20];

    char* ws = (char*)d_ws;
    u64* XA  = (u64*)(ws + OFF_XA);
    u64* XB  = (u64*)(ws + OFF_XB);
    u64* Wp1 = (u64*)(ws + OFF_WP1);
    u64* Wp2 = (u64*)(ws + OFF_WP2);
    u64* Wp3 = (u64*)(ws + OFF_WP3);
    u64* Wp4 = (u64*)(ws + OFF_WP4);
    int2* TH = (int2*)(ws + OFF_TH);

    int nprep = NB_X + 3 * NB_W + NB_W4 + NB_TH;
    prep_kernel<<<nprep, 256, 0, stream>>>(x, W1, W2, W3, W4,
                                           g1, b1, m1, v1, g2, b2, m2, v2,
                                           g3, b3, m3, v3,
                                           XA, Wp1, Wp2, Wp3, Wp4, TH);

    gemm_bin_kernel<<<1024, 256, 0, stream>>>((const uint4*)XA, (const uint4*)Wp1, TH,        XB);
    gemm_bin_kernel<<<1024, 256, 0, stream>>>((const uint4*)XB, (const uint4*)Wp2, TH + 1024, XA);
    gemm_bin_kernel<<<1024, 256, 0, stream>>>((const uint4*)XA, (const uint4*)Wp3, TH + 2048, XB);

    final_layer_kernel<<<64, 256, 0, stream>>>((const uint4*)XB, Wp4, tw, tb, tm, tv,
                                               (float*)d_out);
}

// Round 4
// 298.348 us; speedup vs baseline: 1.9426x; 1.9426x over previous
//
#include <hip/hip_runtime.h>
#include <stdint.h>

typedef unsigned long long u64;

#define BATCH 16384
#define FEAT  1024
#define KW    16          // 1024 bits / 64 per row (= 8 uint4 per row)
#define NCLS  10

// ---- workspace layout (bytes) ----
#define OFF_XA   ((size_t)0)
#define OFF_XB   ((size_t)(2u * 1024u * 1024u))
#define OFF_WP1  ((size_t)(4u * 1024u * 1024u))          // 128 KB each
#define OFF_WP2  (OFF_WP1 + (size_t)FEAT * KW * 8)
#define OFF_WP3  (OFF_WP2 + (size_t)FEAT * KW * 8)
#define OFF_WP4  (OFF_WP3 + (size_t)FEAT * KW * 8)       // 160 u64 = 1280 B
#define OFF_TH   (OFF_WP4 + (size_t)2048)                 // 3*1024 int2 = 24 KB

// ---------------------------------------------------------------------------
// Fused prep: pack sign bits of x (thr 0.5) and W1..W4 (thr 0.0), plus the
// per-column BN integer thresholds. Block-uniform branch on blockIdx ranges.
#define NB_X   65536           // 16384*1024/256
#define NB_W   4096            // 1024*1024/256
#define NB_W4  40              // 10*1024/256
#define NB_TH  12              // 3*1024/256

__global__ void __launch_bounds__(256) prep_kernel(
    const float* __restrict__ x,
    const float* __restrict__ W1, const float* __restrict__ W2,
    const float* __restrict__ W3, const float* __restrict__ W4,
    const float* __restrict__ g1, const float* __restrict__ b1,
    const float* __restrict__ m1, const float* __restrict__ v1,
    const float* __restrict__ g2, const float* __restrict__ b2,
    const float* __restrict__ m2, const float* __restrict__ v2,
    const float* __restrict__ g3, const float* __restrict__ b3,
    const float* __restrict__ m3, const float* __restrict__ v3,
    u64* __restrict__ XA, u64* __restrict__ Wp1, u64* __restrict__ Wp2,
    u64* __restrict__ Wp3, u64* __restrict__ Wp4, int2* __restrict__ TH)
{
    int b = blockIdx.x;
    if (b >= NB_X + 3 * NB_W + NB_W4) {
        // BN thresholds: y = (h-m)*s + b >= 0, s = g*rsqrt(v+eps)
        int gid = (b - (NB_X + 3 * NB_W + NB_W4)) * 256 + threadIdx.x; // 0..3071
        int l = gid >> 10, j = gid & 1023;
        const float *g, *bb, *m, *v;
        if (l == 0)      { g = g1; bb = b1; m = m1; v = v1; }
        else if (l == 1) { g = g2; bb = b2; m = m2; v = v2; }
        else             { g = g3; bb = b3; m = m3; v = v3; }
        double gd = (double)g[j], bd = (double)bb[j], md = (double)m[j], vd = (double)v[j];
        double s = gd / sqrt(vd + 1e-5);
        int ti, flip;
        if (s > 0.0)      { ti = (int)ceil(md - bd / s);  flip = 0; }
        else if (s < 0.0) { ti = (int)floor(md - bd / s); flip = 1; }
        else              { ti = (bd >= 0.0) ? -2000000 : 2000000; flip = 0; }
        TH[gid] = make_int2(ti, flip);
        return;
    }
    const float* src; u64* dst; float thr; int base;
    if (b < NB_X)                    { src = x;  dst = XA;  thr = 0.5f; base = b; }
    else if (b < NB_X + NB_W)        { src = W1; dst = Wp1; thr = 0.0f; base = b - NB_X; }
    else if (b < NB_X + 2 * NB_W)    { src = W2; dst = Wp2; thr = 0.0f; base = b - (NB_X + NB_W); }
    else if (b < NB_X + 3 * NB_W)    { src = W3; dst = Wp3; thr = 0.0f; base = b - (NB_X + 2 * NB_W); }
    else                             { src = W4; dst = Wp4; thr = 0.0f; base = b - (NB_X + 3 * NB_W); }
    int i = base * 256 + threadIdx.x;
    bool bit = src[i] >= thr;
    u64 m = __ballot(bit);
    if ((threadIdx.x & 63) == 0) dst[i >> 6] = m;
}

// ---------------------------------------------------------------------------
// Binary GEMM layer. 128x128 tile / 256 threads, 8x8 register tile.
// LDS stored as uint4 pair-slots with slot = q ^ ((row>>3)&7).
// NOTE: plain __launch_bounds__(256). The R3 (256,4) variant forced VGPR=64
// and spilled the 64-reg accumulator tile to scratch (FETCH 229MB/WRITE 416MB,
// 3x slowdown). ~115 VGPRs still gives 4 waves/EU; do NOT cap.
__global__ void __launch_bounds__(256)
gemm_bin_kernel(const uint4* __restrict__ Xin, const uint4* __restrict__ Wp,
                const int2* __restrict__ th, u64* __restrict__ Xout) {
    __shared__ uint4 Xs[128][8];
    __shared__ uint4 Ws[128][8];

    const int tid = threadIdx.x;
    const int bx = blockIdx.x & 7;    // col block
    const int by = blockIdx.x >> 3;   // row block

    const uint4* Xg = Xin + (size_t)by * 128 * 8;   // 16 KB contiguous
    const uint4* Wg = Wp + (size_t)bx * 128 * 8;

#pragma unroll
    for (int i = 0; i < 4; ++i) {
        int idx = tid + i * 256;          // uint4 index 0..1023
        int row = idx >> 3;
        int q = idx & 7;
        int c = (row >> 3) & 7;
        Xs[row][q ^ c] = Xg[idx];
        Ws[row][q ^ c] = Wg[idx];
    }
    __syncthreads();

    const int tr = tid >> 4;    // 0..15 -> rows tr*8..tr*8+7
    const int tc = tid & 15;    // 0..15 -> cols tc*8..tc*8+7
    const int cx = tr & 7;
    const int cw = tc & 7;

    int acc[8][8];
#pragma unroll
    for (int i = 0; i < 8; ++i)
#pragma unroll
        for (int j = 0; j < 8; ++j) acc[i][j] = 0;

#pragma unroll 1
    for (int p = 0; p < 8; ++p) {
        uint4 xw[8];
#pragma unroll
        for (int i = 0; i < 8; ++i) xw[i] = Xs[tr * 8 + i][p ^ cx];
#pragma unroll
        for (int j = 0; j < 8; ++j) {
            uint4 wv = Ws[tc * 8 + j][p ^ cw];
#pragma unroll
            for (int i = 0; i < 8; ++i) {
                acc[i][j] += __popc(xw[i].x ^ wv.x) + __popc(xw[i].y ^ wv.y)
                           + __popc(xw[i].z ^ wv.z) + __popc(xw[i].w ^ wv.w);
            }
        }
    }

    int2 t8[8];
#pragma unroll
    for (int j = 0; j < 8; ++j) t8[j] = th[bx * 128 + tc * 8 + j];

    __syncthreads();
    // Reuse Xs as a 128x16 byte tile: byte (row, tc) = bits for cols tc*8..+7
    unsigned char* Bb = (unsigned char*)&Xs[0][0];
#pragma unroll
    for (int i = 0; i < 8; ++i) {
        unsigned int byte = 0;
#pragma unroll
        for (int j = 0; j < 8; ++j) {
            int h = 1024 - 2 * acc[i][j];
            int bit = t8[j].y ? (h <= t8[j].x) : (h >= t8[j].x);
            byte |= (unsigned int)bit << j;
        }
        Bb[(tr * 8 + i) * 16 + tc] = (unsigned char)byte;
    }
    __syncthreads();

    int lrow = tid >> 1, half = tid & 1;
    u64 word = *(const u64*)&Bb[lrow * 16 + half * 8];
    Xout[(size_t)(by * 128 + lrow) * KW + bx * 2 + half] = word;
}

// ---------------------------------------------------------------------------
// Final 1024 -> 10 binary matmul + TensorNorm. One row per thread, W4 in LDS.
// One row of packed bits = 16 u64 = 8 uint4.
__global__ void __launch_bounds__(256) final_layer_kernel(
    const uint4* __restrict__ X3, const u64* __restrict__ W4p,
    const float* __restrict__ tw, const float* __restrict__ tb,
    const float* __restrict__ tm, const float* __restrict__ tv,
    float* __restrict__ out) {
    __shared__ u64 Wl[NCLS * KW];   // 160 u64 = 80 uint4
    if (threadIdx.x < NCLS * KW) Wl[threadIdx.x] = W4p[threadIdx.x];
    __syncthreads();

    int row = blockIdx.x * 256 + threadIdx.x;   // 64 blocks -> 16384 rows
    uint4 xr[8];
#pragma unroll
    for (int t = 0; t < 8; ++t) xr[t] = X3[(size_t)row * 8 + t];

    double sc = (double)tw[0] / sqrt((double)tv[0] + 1e-4);
    double off = (double)tb[0] - (double)tm[0] * sc;

    const uint4* Wl4 = (const uint4*)Wl;
#pragma unroll
    for (int c = 0; c < NCLS; ++c) {
        int p = 0;
#pragma unroll
        for (int t = 0; t < 8; ++t) {
            uint4 wv = Wl4[c * 8 + t];
            p += __popc(xr[t].x ^ wv.x) + __popc(xr[t].y ^ wv.y)
               + __popc(xr[t].z ^ wv.z) + __popc(xr[t].w ^ wv.w);
        }
        int h = 1024 - 2 * p;
        out[(size_t)row * NCLS + c] = (float)((double)h * sc + off);
    }
}

// ---------------------------------------------------------------------------
extern "C" void kernel_launch(void* const* d_in, const int* in_sizes, int n_in,
                              void* d_out, int out_size, void* d_ws, size_t ws_size,
                              hipStream_t stream) {
    const float* x  = (const float*)d_in[0];
    const float* W1 = (const float*)d_in[1];
    const float* W2 = (const float*)d_in[2];
    const float* W3 = (const float*)d_in[3];
    const float* W4 = (const float*)d_in[4];
    const float* g1 = (const float*)d_in[5];
    const float* b1 = (const float*)d_in[6];
    const float* m1 = (const float*)d_in[7];
    const float* v1 = (const float*)d_in[8];
    const float* g2 = (const float*)d_in[9];
    const float* b2 = (const float*)d_in[10];
    const float* m2 = (const float*)d_in[11];
    const float* v2 = (const float*)d_in[12];
    const float* g3 = (const float*)d_in[13];
    const float* b3 = (const float*)d_in[14];
    const float* m3 = (const float*)d_in[15];
    const float* v3 = (const float*)d_in[16];
    const float* tw = (const float*)d_in[17];
    const float* tb = (const float*)d_in[18];
    const float* tm = (const float*)d_in[19];
    const float* tv = (const float*)d_in[20];

    char* ws = (char*)d_ws;
    u64* XA  = (u64*)(ws + OFF_XA);
    u64* XB  = (u64*)(ws + OFF_XB);
    u64* Wp1 = (u64*)(ws + OFF_WP1);
    u64* Wp2 = (u64*)(ws + OFF_WP2);
    u64* Wp3 = (u64*)(ws + OFF_WP3);
    u64* Wp4 = (u64*)(ws + OFF_WP4);
    int2* TH = (int2*)(ws + OFF_TH);

    int nprep = NB_X + 3 * NB_W + NB_W4 + NB_TH;
    prep_kernel<<<nprep, 256, 0, stream>>>(x, W1, W2, W3, W4,
                                           g1, b1, m1, v1, g2, b2, m2, v2,
                                           g3, b3, m3, v3,
                                           XA, Wp1, Wp2, Wp3, Wp4, TH);

    gemm_bin_kernel<<<1024, 256, 0, stream>>>((const uint4*)XA, (const uint4*)Wp1, TH,        XB);
    gemm_bin_kernel<<<1024, 256, 0, stream>>>((const uint4*)XB, (const uint4*)Wp2, TH + 1024, XA);
    gemm_bin_kernel<<<1024, 256, 0, stream>>>((const uint4*)XA, (const uint4*)Wp3, TH + 2048, XB);

    final_layer_kernel<<<64, 256, 0, stream>>>((const uint4*)XB, Wp4, tw, tb, tm, tv,
                                               (float*)d_out);
}

// Round 5
// 287.252 us; speedup vs baseline: 2.0176x; 1.0386x over previous
//
#include <hip/hip_runtime.h>
#include <stdint.h>

typedef unsigned long long u64;

#define BATCH 16384
#define FEAT  1024
#define KW    16          // 1024 bits / 64 per row
#define NCLS  10

#define ROWS_PB 128       // rows per gemm block
#define COLS_PB 64        // cols per gemm block (one packed u64 word)

// ---- workspace layout (bytes) ----
// XA/XB: column-major packed strips, u64 [KW][BATCH] = 2 MB each
#define OFF_XA   ((size_t)0)
#define OFF_XB   ((size_t)(2u * 1024u * 1024u))
#define OFF_WP1  ((size_t)(4u * 1024u * 1024u))          // 128 KB each, row-major
#define OFF_WP2  (OFF_WP1 + (size_t)FEAT * KW * 8)
#define OFF_WP3  (OFF_WP2 + (size_t)FEAT * KW * 8)
#define OFF_WP4  (OFF_WP3 + (size_t)FEAT * KW * 8)       // 160 u64
#define OFF_TH   (OFF_WP4 + (size_t)2048)                 // 3*1024 int2

// ---------------------------------------------------------------------------
// Fused prep. X is packed COLUMN-MAJOR (strip-major): XA[wq*BATCH + row].
// Weights stay row-major: Wp[wrow*KW + wq].
#define NB_X   65536           // 16384*1024/256
#define NB_W   4096            // 1024*1024/256
#define NB_W4  40              // 10*1024/256
#define NB_TH  12              // 3*1024/256

__global__ void __launch_bounds__(256) prep_kernel(
    const float* __restrict__ x,
    const float* __restrict__ W1, const float* __restrict__ W2,
    const float* __restrict__ W3, const float* __restrict__ W4,
    const float* __restrict__ g1, const float* __restrict__ b1,
    const float* __restrict__ m1, const float* __restrict__ v1,
    const float* __restrict__ g2, const float* __restrict__ b2,
    const float* __restrict__ m2, const float* __restrict__ v2,
    const float* __restrict__ g3, const float* __restrict__ b3,
    const float* __restrict__ m3, const float* __restrict__ v3,
    u64* __restrict__ XA, u64* __restrict__ Wp1, u64* __restrict__ Wp2,
    u64* __restrict__ Wp3, u64* __restrict__ Wp4, int2* __restrict__ TH)
{
    int b = blockIdx.x;
    if (b >= NB_X + 3 * NB_W + NB_W4) {
        int gid = (b - (NB_X + 3 * NB_W + NB_W4)) * 256 + threadIdx.x; // 0..3071
        int l = gid >> 10, j = gid & 1023;
        const float *g, *bb, *m, *v;
        if (l == 0)      { g = g1; bb = b1; m = m1; v = v1; }
        else if (l == 1) { g = g2; bb = b2; m = m2; v = v2; }
        else             { g = g3; bb = b3; m = m3; v = v3; }
        double gd = (double)g[j], bd = (double)bb[j], md = (double)m[j], vd = (double)v[j];
        double s = gd / sqrt(vd + 1e-5);
        int ti, flip;
        if (s > 0.0)      { ti = (int)ceil(md - bd / s);  flip = 0; }
        else if (s < 0.0) { ti = (int)floor(md - bd / s); flip = 1; }
        else              { ti = (bd >= 0.0) ? -2000000 : 2000000; flip = 0; }
        TH[gid] = make_int2(ti, flip);
        return;
    }
    if (b < NB_X) {
        // input x: bit = (2x-1 >= 0) <=> x >= 0.5, column-major strips
        int i = b * 256 + threadIdx.x;
        bool bit = x[i] >= 0.5f;
        u64 m = __ballot(bit);
        if ((threadIdx.x & 63) == 0) {
            int row = i >> 10;
            int wq = (i >> 6) & 15;
            XA[(size_t)wq * BATCH + row] = m;
        }
        return;
    }
    const float* src; u64* dst; int base;
    if (b < NB_X + NB_W)             { src = W1; dst = Wp1; base = b - NB_X; }
    else if (b < NB_X + 2 * NB_W)    { src = W2; dst = Wp2; base = b - (NB_X + NB_W); }
    else if (b < NB_X + 3 * NB_W)    { src = W3; dst = Wp3; base = b - (NB_X + 2 * NB_W); }
    else                             { src = W4; dst = Wp4; base = b - (NB_X + 3 * NB_W); }
    int i = base * 256 + threadIdx.x;
    bool bit = src[i] >= 0.0f;
    u64 m = __ballot(bit);
    if ((threadIdx.x & 63) == 0) dst[i >> 6] = m;
}

// ---------------------------------------------------------------------------
// Binary GEMM layer, scatter-free LDS access:
//   - X reads: consecutive lanes -> consecutive rows (pitch 18 u64 = 144 B,
//     bank spread even), one ds_read_b128 per k-slot per thread.
//   - W reads: all lanes of a wave read the SAME address (broadcast, free).
// Block: 128 rows x 64 cols, 256 threads; thread = (row, 32-col half).
// Activations are column-major strips: Xin/Xout[wq*BATCH + row].
__global__ void __launch_bounds__(256)
gemm_bin_kernel(const u64* __restrict__ Xin, const u64* __restrict__ Wp,
                const int2* __restrict__ th, u64* __restrict__ Xout) {
    __shared__ u64  Xs[ROWS_PB][18];     // slots 0..15 used, pitch 18 (144 B)
    __shared__ u64  Ws[COLS_PB * KW];    // 8 KB, row-major
    __shared__ int2 Ts[COLS_PB];

    const int tid = threadIdx.x;
    const int bc = blockIdx.x & 15;      // col block (16 x 64 cols)
    const int br = blockIdx.x >> 4;      // row block (128 x 128 rows)
    const int r0 = br * ROWS_PB;
    const int c0 = bc * COLS_PB;

    // stage X: 2048 u64, coalesced per strip
#pragma unroll
    for (int k = 0; k < 8; ++k) {
        int f = tid + k * 256;           // 0..2047
        int row = f & (ROWS_PB - 1);
        int wq = f >> 7;
        Xs[row][wq] = Xin[(size_t)wq * BATCH + r0 + row];
    }
    // stage W: 1024 u64, contiguous
#pragma unroll
    for (int k = 0; k < 4; ++k) {
        int f = tid + k * 256;
        Ws[f] = Wp[(size_t)c0 * KW + f];
    }
    if (tid < COLS_PB) Ts[tid] = th[c0 + tid];
    __syncthreads();

    const int row = tid & (ROWS_PB - 1);
    const int ch  = tid >> 7;            // 0/1 -> cols ch*32 .. ch*32+31
    const uint4* xrow  = (const uint4*)&Xs[row][0];
    const uint4* wbase = (const uint4*)&Ws[ch * 32 * KW];

    int acc[32];
#pragma unroll
    for (int j = 0; j < 32; ++j) acc[j] = 0;

#pragma unroll 1
    for (int sx = 0; sx < 8; ++sx) {
        uint4 xw = xrow[sx];
#pragma unroll
        for (int jc = 0; jc < 4; ++jc) {
            uint4 wv[8];
#pragma unroll
            for (int u = 0; u < 8; ++u)
                wv[u] = wbase[(jc * 8 + u) * 8 + sx];   // broadcast reads
#pragma unroll
            for (int u = 0; u < 8; ++u) {
                acc[jc * 8 + u] += __popc(xw.x ^ wv[u].x) + __popc(xw.y ^ wv[u].y)
                                 + __popc(xw.z ^ wv[u].z) + __popc(xw.w ^ wv[u].w);
            }
        }
    }

    // epilogue: 32 threshold bits -> one u32 half of the output word
    unsigned int bits = 0;
#pragma unroll
    for (int j = 0; j < 32; ++j) {
        int2 t = Ts[ch * 32 + j];
        int h = 1024 - 2 * acc[j];
        int bit = t.y ? (h <= t.x) : (h >= t.x);
        bits |= (unsigned int)bit << j;
    }
    unsigned int* out32 = (unsigned int*)Xout;
    out32[((size_t)bc * BATCH + r0 + row) * 2 + ch] = bits;
}

// ---------------------------------------------------------------------------
// Final 1024 -> 10 binary matmul + TensorNorm. X3 is column-major strips,
// so each strip load is fully coalesced across the wave.
__global__ void __launch_bounds__(256) final_layer_kernel(
    const u64* __restrict__ X3, const u64* __restrict__ W4p,
    const float* __restrict__ tw, const float* __restrict__ tb,
    const float* __restrict__ tm, const float* __restrict__ tv,
    float* __restrict__ out) {
    __shared__ u64 Wl[NCLS * KW];   // 160 u64
    if (threadIdx.x < NCLS * KW) Wl[threadIdx.x] = W4p[threadIdx.x];
    __syncthreads();

    int row = blockIdx.x * 256 + threadIdx.x;   // 64 blocks -> 16384 rows
    u64 xr[KW];
#pragma unroll
    for (int wq = 0; wq < KW; ++wq) xr[wq] = X3[(size_t)wq * BATCH + row];

    double sc = (double)tw[0] / sqrt((double)tv[0] + 1e-4);
    double off = (double)tb[0] - (double)tm[0] * sc;

#pragma unroll
    for (int c = 0; c < NCLS; ++c) {
        int p = 0;
#pragma unroll
        for (int wq = 0; wq < KW; ++wq)
            p += __builtin_popcountll(xr[wq] ^ Wl[c * KW + wq]);
        int h = 1024 - 2 * p;
        out[(size_t)row * NCLS + c] = (float)((double)h * sc + off);
    }
}

// ---------------------------------------------------------------------------
extern "C" void kernel_launch(void* const* d_in, const int* in_sizes, int n_in,
                              void* d_out, int out_size, void* d_ws, size_t ws_size,
                              hipStream_t stream) {
    const float* x  = (const float*)d_in[0];
    const float* W1 = (const float*)d_in[1];
    const float* W2 = (const float*)d_in[2];
    const float* W3 = (const float*)d_in[3];
    const float* W4 = (const float*)d_in[4];
    const float* g1 = (const float*)d_in[5];
    const float* b1 = (const float*)d_in[6];
    const float* m1 = (const float*)d_in[7];
    const float* v1 = (const float*)d_in[8];
    const float* g2 = (const float*)d_in[9];
    const float* b2 = (const float*)d_in[10];
    const float* m2 = (const float*)d_in[11];
    const float* v2 = (const float*)d_in[12];
    const float* g3 = (const float*)d_in[13];
    const float* b3 = (const float*)d_in[14];
    const float* m3 = (const float*)d_in[15];
    const float* v3 = (const float*)d_in[16];
    const float* tw = (const float*)d_in[17];
    const float* tb = (const float*)d_in[18];
    const float* tm = (const float*)d_in[19];
    const float* tv = (const float*)d_in[20];

    char* ws = (char*)d_ws;
    u64* XA  = (u64*)(ws + OFF_XA);
    u64* XB  = (u64*)(ws + OFF_XB);
    u64* Wp1 = (u64*)(ws + OFF_WP1);
    u64* Wp2 = (u64*)(ws + OFF_WP2);
    u64* Wp3 = (u64*)(ws + OFF_WP3);
    u64* Wp4 = (u64*)(ws + OFF_WP4);
    int2* TH = (int2*)(ws + OFF_TH);

    int nprep = NB_X + 3 * NB_W + NB_W4 + NB_TH;
    prep_kernel<<<nprep, 256, 0, stream>>>(x, W1, W2, W3, W4,
                                           g1, b1, m1, v1, g2, b2, m2, v2,
                                           g3, b3, m3, v3,
                                           XA, Wp1, Wp2, Wp3, Wp4, TH);

    gemm_bin_kernel<<<2048, 256, 0, stream>>>(XA, Wp1, TH,        XB);
    gemm_bin_kernel<<<2048, 256, 0, stream>>>(XB, Wp2, TH + 1024, XA);
    gemm_bin_kernel<<<2048, 256, 0, stream>>>(XA, Wp3, TH + 2048, XB);

    final_layer_kernel<<<64, 256, 0, stream>>>(XB, Wp4, tw, tb, tm, tv,
                                               (float*)d_out);
}

// Round 6
// 279.323 us; speedup vs baseline: 2.0749x; 1.0284x over previous
//
#include <hip/hip_runtime.h>
#include <stdint.h>

typedef unsigned long long u64;

#define BATCH 16384
#define FEAT  1024
#define KW    16          // 1024 bits / 64 per row
#define NCLS  10

// ---- workspace layout (bytes) ----
// XA/XB: column-major packed strips, u64 [KW][BATCH] = 2 MB each
#define OFF_XA   ((size_t)0)
#define OFF_XB   ((size_t)(2u * 1024u * 1024u))
#define OFF_WP1  ((size_t)(4u * 1024u * 1024u))          // 128 KB each, row-major
#define OFF_WP2  (OFF_WP1 + (size_t)FEAT * KW * 8)
#define OFF_WP3  (OFF_WP2 + (size_t)FEAT * KW * 8)
#define OFF_WP4  (OFF_WP3 + (size_t)FEAT * KW * 8)       // 160 u64
#define OFF_TH   (OFF_WP4 + (size_t)2048)                 // 3*1024 int2

// ---------------------------------------------------------------------------
// Fused prep, float4 + shuffle-combine packing (4 elems/thread).
// x -> column-major strips XA[wq*BATCH+row]; weights -> row-major words.
#define NB_X   16384           // 16384*1024 / (256*4)
#define NB_W   1024            // 1024*1024 / (256*4)
#define NB_W4  10              // 10*1024  / (256*4)
#define NB_TH  12              // 3*1024/256

__global__ void __launch_bounds__(256) prep_kernel(
    const float* __restrict__ x,
    const float* __restrict__ W1, const float* __restrict__ W2,
    const float* __restrict__ W3, const float* __restrict__ W4,
    const float* __restrict__ g1, const float* __restrict__ b1,
    const float* __restrict__ m1, const float* __restrict__ v1,
    const float* __restrict__ g2, const float* __restrict__ b2,
    const float* __restrict__ m2, const float* __restrict__ v2,
    const float* __restrict__ g3, const float* __restrict__ b3,
    const float* __restrict__ m3, const float* __restrict__ v3,
    u64* __restrict__ XA, u64* __restrict__ Wp1, u64* __restrict__ Wp2,
    u64* __restrict__ Wp3, u64* __restrict__ Wp4, int2* __restrict__ TH)
{
    int b = blockIdx.x;
    if (b >= NB_X + 3 * NB_W + NB_W4) {
        int gid = (b - (NB_X + 3 * NB_W + NB_W4)) * 256 + threadIdx.x; // 0..3071
        int l = gid >> 10, j = gid & 1023;
        const float *g, *bb, *m, *v;
        if (l == 0)      { g = g1; bb = b1; m = m1; v = v1; }
        else if (l == 1) { g = g2; bb = b2; m = m2; v = v2; }
        else             { g = g3; bb = b3; m = m3; v = v3; }
        double gd = (double)g[j], bd = (double)bb[j], md = (double)m[j], vd = (double)v[j];
        double s = gd / sqrt(vd + 1e-5);
        int ti, flip;
        if (s > 0.0)      { ti = (int)ceil(md - bd / s);  flip = 0; }
        else if (s < 0.0) { ti = (int)floor(md - bd / s); flip = 1; }
        else              { ti = (bd >= 0.0) ? -2000000 : 2000000; flip = 0; }
        TH[gid] = make_int2(ti, flip);
        return;
    }
    const float* src; u64* dst; float thr; int base; int isX = 0;
    if (b < NB_X)                    { src = x;  dst = XA;  thr = 0.5f; base = b; isX = 1; }
    else if (b < NB_X + NB_W)        { src = W1; dst = Wp1; thr = 0.0f; base = b - NB_X; }
    else if (b < NB_X + 2 * NB_W)    { src = W2; dst = Wp2; thr = 0.0f; base = b - (NB_X + NB_W); }
    else if (b < NB_X + 3 * NB_W)    { src = W3; dst = Wp3; thr = 0.0f; base = b - (NB_X + 2 * NB_W); }
    else                             { src = W4; dst = Wp4; thr = 0.0f; base = b - (NB_X + 3 * NB_W); }

    int e0 = base * 1024 + threadIdx.x * 4;        // first element of my float4
    float4 xv = *(const float4*)(src + e0);
    unsigned int nib = (xv.x >= thr ? 1u : 0u) | (xv.y >= thr ? 2u : 0u)
                     | (xv.z >= thr ? 4u : 0u) | (xv.w >= thr ? 8u : 0u);
    unsigned int b8  = nib | (__shfl_xor(nib, 1) << 4);
    unsigned int b16 = b8  | (__shfl_xor(b8, 2) << 8);
    unsigned int b32 = b16 | (__shfl_xor(b16, 4) << 16);
    u64 word = (u64)b32 | ((u64)__shfl_xor(b32, 8) << 32);
    int lane = threadIdx.x & 63;
    if ((lane & 15) == 0) {
        int g = e0 >> 6;               // lane L: e0 = wavebase + L*4 -> word wavebase/64 + L/16
        if (isX) { int row = g >> 4, wq = g & 15; XA[(size_t)wq * BATCH + row] = word; }
        else dst[g] = word;
    }
}

// ---------------------------------------------------------------------------
// Binary GEMM layer. 128 rows x 128 cols per 256-thread block.
// Thread = rows {lane, lane+64}; wave = 32 cols (wave-uniform!).
// X in LDS (pitch-18 u64, lane-indexed b128 reads).
// W + thresholds via SCALAR loads from global (wave-uniform addresses via
// readfirstlane) -> v_xor_b32 v,s,v: W costs no VGPRs and no LDS traffic.
// Col-groups of 8 processed to completion so only 16 accs live (low VGPR).
__global__ void __launch_bounds__(256)
gemm_bin_kernel(const u64* __restrict__ Xin, const u64* __restrict__ Wp,
                const int2* __restrict__ th, u64* __restrict__ Xout) {
    __shared__ u64 Xs[128][18];      // slots 0..15 used, pitch 144 B

    const int tid = threadIdx.x;
    const int bc = blockIdx.x & 7;    // col block (8 x 128 cols)
    const int br = blockIdx.x >> 3;   // row block
    const int r0 = br * 128;

    // stage X: 2048 u64, coalesced per strip
#pragma unroll
    for (int k = 0; k < 8; ++k) {
        int f = tid + k * 256;
        int row = f & 127;
        int wq = f >> 7;
        Xs[row][wq] = Xin[(size_t)wq * BATCH + r0 + row];
    }
    __syncthreads();

    const int lane = tid & 63;
    const int w = __builtin_amdgcn_readfirstlane(tid >> 6);   // wave id, SGPR
    const int cbase = bc * 128 + w * 32;                      // scalar

    const uint4* xrowA = (const uint4*)&Xs[lane][0];
    const uint4* xrowB = (const uint4*)&Xs[lane + 64][0];

    unsigned int bitsA = 0, bitsB = 0;

#pragma unroll 1
    for (int jc = 0; jc < 4; ++jc) {
        int accA[8], accB[8];
#pragma unroll
        for (int u = 0; u < 8; ++u) { accA[u] = 0; accB[u] = 0; }

#pragma unroll 1
        for (int sp = 0; sp < 4; ++sp) {          // sx pairs
            uint4 xa0 = xrowA[sp * 2], xa1 = xrowA[sp * 2 + 1];
            uint4 xb0 = xrowB[sp * 2], xb1 = xrowB[sp * 2 + 1];
#pragma unroll
            for (int u = 0; u < 8; ++u) {
                const uint4* wrow = (const uint4*)(Wp + (size_t)(cbase + jc * 8 + u) * KW);
                uint4 wv0 = wrow[sp * 2];          // scalar loads (uniform addr)
                uint4 wv1 = wrow[sp * 2 + 1];
                accA[u] += __popc(xa0.x ^ wv0.x) + __popc(xa0.y ^ wv0.y)
                         + __popc(xa0.z ^ wv0.z) + __popc(xa0.w ^ wv0.w)
                         + __popc(xa1.x ^ wv1.x) + __popc(xa1.y ^ wv1.y)
                         + __popc(xa1.z ^ wv1.z) + __popc(xa1.w ^ wv1.w);
                accB[u] += __popc(xb0.x ^ wv0.x) + __popc(xb0.y ^ wv0.y)
                         + __popc(xb0.z ^ wv0.z) + __popc(xb0.w ^ wv0.w)
                         + __popc(xb1.x ^ wv1.x) + __popc(xb1.y ^ wv1.y)
                         + __popc(xb1.z ^ wv1.z) + __popc(xb1.w ^ wv1.w);
            }
        }
        // thresholds for these 8 cols (scalar loads), fold into bit words
#pragma unroll
        for (int u = 0; u < 8; ++u) {
            int2 t = th[cbase + jc * 8 + u];
            int hA = 1024 - 2 * accA[u];
            int hB = 1024 - 2 * accB[u];
            unsigned int ba = t.y ? (hA <= t.x) : (hA >= t.x);
            unsigned int bb = t.y ? (hB <= t.x) : (hB >= t.x);
            bitsA |= ba << (jc * 8 + u);
            bitsB |= bb << (jc * 8 + u);
        }
    }

    // store: output strips as u32 halves; wq = cbase>>6, half = (cbase>>5)&1
    const int wq = cbase >> 6;
    const int half = (cbase >> 5) & 1;
    unsigned int* out32 = (unsigned int*)Xout;
    out32[(size_t)wq * 2 * BATCH + (r0 + lane) * 2 + half] = bitsA;
    out32[(size_t)wq * 2 * BATCH + (r0 + lane + 64) * 2 + half] = bitsB;
}

// ---------------------------------------------------------------------------
// Final 1024 -> 10 binary matmul + TensorNorm. X3 column-major strips.
__global__ void __launch_bounds__(256) final_layer_kernel(
    const u64* __restrict__ X3, const u64* __restrict__ W4p,
    const float* __restrict__ tw, const float* __restrict__ tb,
    const float* __restrict__ tm, const float* __restrict__ tv,
    float* __restrict__ out) {
    __shared__ u64 Wl[NCLS * KW];
    if (threadIdx.x < NCLS * KW) Wl[threadIdx.x] = W4p[threadIdx.x];
    __syncthreads();

    int row = blockIdx.x * 256 + threadIdx.x;
    u64 xr[KW];
#pragma unroll
    for (int wq = 0; wq < KW; ++wq) xr[wq] = X3[(size_t)wq * BATCH + row];

    double sc = (double)tw[0] / sqrt((double)tv[0] + 1e-4);
    double off = (double)tb[0] - (double)tm[0] * sc;

#pragma unroll
    for (int c = 0; c < NCLS; ++c) {
        int p = 0;
#pragma unroll
        for (int wq = 0; wq < KW; ++wq)
            p += __builtin_popcountll(xr[wq] ^ Wl[c * KW + wq]);
        int h = 1024 - 2 * p;
        out[(size_t)row * NCLS + c] = (float)((double)h * sc + off);
    }
}

// ---------------------------------------------------------------------------
extern "C" void kernel_launch(void* const* d_in, const int* in_sizes, int n_in,
                              void* d_out, int out_size, void* d_ws, size_t ws_size,
                              hipStream_t stream) {
    const float* x  = (const float*)d_in[0];
    const float* W1 = (const float*)d_in[1];
    const float* W2 = (const float*)d_in[2];
    const float* W3 = (const float*)d_in[3];
    const float* W4 = (const float*)d_in[4];
    const float* g1 = (const float*)d_in[5];
    const float* b1 = (const float*)d_in[6];
    const float* m1 = (const float*)d_in[7];
    const float* v1 = (const float*)d_in[8];
    const float* g2 = (const float*)d_in[9];
    const float* b2 = (const float*)d_in[10];
    const float* m2 = (const float*)d_in[11];
    const float* v2 = (const float*)d_in[12];
    const float* g3 = (const float*)d_in[13];
    const float* b3 = (const float*)d_in[14];
    const float* m3 = (const float*)d_in[15];
    const float* v3 = (const float*)d_in[16];
    const float* tw = (const float*)d_in[17];
    const float* tb = (const float*)d_in[18];
    const float* tm = (const float*)d_in[19];
    const float* tv = (const float*)d_in[20];

    char* ws = (char*)d_ws;
    u64* XA  = (u64*)(ws + OFF_XA);
    u64* XB  = (u64*)(ws + OFF_XB);
    u64* Wp1 = (u64*)(ws + OFF_WP1);
    u64* Wp2 = (u64*)(ws + OFF_WP2);
    u64* Wp3 = (u64*)(ws + OFF_WP3);
    u64* Wp4 = (u64*)(ws + OFF_WP4);
    int2* TH = (int2*)(ws + OFF_TH);

    int nprep = NB_X + 3 * NB_W + NB_W4 + NB_TH;
    prep_kernel<<<nprep, 256, 0, stream>>>(x, W1, W2, W3, W4,
                                           g1, b1, m1, v1, g2, b2, m2, v2,
                                           g3, b3, m3, v3,
                                           XA, Wp1, Wp2, Wp3, Wp4, TH);

    gemm_bin_kernel<<<1024, 256, 0, stream>>>(XA, Wp1, TH,        XB);
    gemm_bin_kernel<<<1024, 256, 0, stream>>>(XB, Wp2, TH + 1024, XA);
    gemm_bin_kernel<<<1024, 256, 0, stream>>>(XA, Wp3, TH + 2048, XB);

    final_layer_kernel<<<64, 256, 0, stream>>>(XB, Wp4, tw, tb, tm, tv,
                                               (float*)d_out);
}

// Round 7
// 256.037 us; speedup vs baseline: 2.2636x; 1.0909x over previous
//
#include <hip/hip_runtime.h>
#include <stdint.h>

typedef unsigned long long u64;

#define BATCH 16384
#define FEAT  1024
#define KW    16          // 1024 bits / 64 per row
#define NCLS  10

// ---- workspace layout (bytes) ----
// XA/XB: column-major packed strips, u64 [KW][BATCH] = 2 MB each
#define OFF_XA   ((size_t)0)
#define OFF_XB   ((size_t)(2u * 1024u * 1024u))
#define OFF_WP1  ((size_t)(4u * 1024u * 1024u))          // 128 KB each, row-major
#define OFF_WP2  (OFF_WP1 + (size_t)FEAT * KW * 8)
#define OFF_WP3  (OFF_WP2 + (size_t)FEAT * KW * 8)
#define OFF_WP4  (OFF_WP3 + (size_t)FEAT * KW * 8)       // 160 u64
#define OFF_TH   (OFF_WP4 + (size_t)2048)                 // 3*1024 int2

// ---------------------------------------------------------------------------
// Fused prep, float4 + shuffle-combine packing (4 elems/thread).
#define NB_X   16384           // 16384*1024 / (256*4)
#define NB_W   1024            // 1024*1024 / (256*4)
#define NB_W4  10              // 10*1024  / (256*4)
#define NB_TH  12              // 3*1024/256

__global__ void __launch_bounds__(256) prep_kernel(
    const float* __restrict__ x,
    const float* __restrict__ W1, const float* __restrict__ W2,
    const float* __restrict__ W3, const float* __restrict__ W4,
    const float* __restrict__ g1, const float* __restrict__ b1,
    const float* __restrict__ m1, const float* __restrict__ v1,
    const float* __restrict__ g2, const float* __restrict__ b2,
    const float* __restrict__ m2, const float* __restrict__ v2,
    const float* __restrict__ g3, const float* __restrict__ b3,
    const float* __restrict__ m3, const float* __restrict__ v3,
    u64* __restrict__ XA, u64* __restrict__ Wp1, u64* __restrict__ Wp2,
    u64* __restrict__ Wp3, u64* __restrict__ Wp4, int2* __restrict__ TH)
{
    int b = blockIdx.x;
    if (b >= NB_X + 3 * NB_W + NB_W4) {
        int gid = (b - (NB_X + 3 * NB_W + NB_W4)) * 256 + threadIdx.x; // 0..3071
        int l = gid >> 10, j = gid & 1023;
        const float *g, *bb, *m, *v;
        if (l == 0)      { g = g1; bb = b1; m = m1; v = v1; }
        else if (l == 1) { g = g2; bb = b2; m = m2; v = v2; }
        else             { g = g3; bb = b3; m = m3; v = v3; }
        double gd = (double)g[j], bd = (double)bb[j], md = (double)m[j], vd = (double)v[j];
        double s = gd / sqrt(vd + 1e-5);
        int ti, flip;
        if (s > 0.0)      { ti = (int)ceil(md - bd / s);  flip = 0; }
        else if (s < 0.0) { ti = (int)floor(md - bd / s); flip = 1; }
        else              { ti = (bd >= 0.0) ? -2000000 : 2000000; flip = 0; }
        TH[gid] = make_int2(ti, flip);
        return;
    }
    const float* src; u64* dst; float thr; int base; int isX = 0;
    if (b < NB_X)                    { src = x;  dst = XA;  thr = 0.5f; base = b; isX = 1; }
    else if (b < NB_X + NB_W)        { src = W1; dst = Wp1; thr = 0.0f; base = b - NB_X; }
    else if (b < NB_X + 2 * NB_W)    { src = W2; dst = Wp2; thr = 0.0f; base = b - (NB_X + NB_W); }
    else if (b < NB_X + 3 * NB_W)    { src = W3; dst = Wp3; thr = 0.0f; base = b - (NB_X + 2 * NB_W); }
    else                             { src = W4; dst = Wp4; thr = 0.0f; base = b - (NB_X + 3 * NB_W); }

    int e0 = base * 1024 + threadIdx.x * 4;
    float4 xv = *(const float4*)(src + e0);
    unsigned int nib = (xv.x >= thr ? 1u : 0u) | (xv.y >= thr ? 2u : 0u)
                     | (xv.z >= thr ? 4u : 0u) | (xv.w >= thr ? 8u : 0u);
    unsigned int b8  = nib | (__shfl_xor(nib, 1) << 4);
    unsigned int b16 = b8  | (__shfl_xor(b8, 2) << 8);
    unsigned int b32 = b16 | (__shfl_xor(b16, 4) << 16);
    u64 word = (u64)b32 | ((u64)__shfl_xor(b32, 8) << 32);
    int lane = threadIdx.x & 63;
    if ((lane & 15) == 0) {
        int g = e0 >> 6;
        if (isX) { int row = g >> 4, wq = g & 15; XA[(size_t)wq * BATCH + row] = word; }
        else dst[g] = word;
    }
}

// ---------------------------------------------------------------------------
// XNOR-MAC of one uint4 of X against one uint4 of W (scalar), accumulating.
// Pinned with inline asm: acc stays "+v", W stays "s", exactly 8 VALU insts.
#define MACQ(acc, xv, wv)                                                   \
    { unsigned int t_;                                                      \
      asm("v_xor_b32 %0, %6, %2\n\t"                                        \
          "v_bcnt_u32_b32 %1, %0, %1\n\t"                                   \
          "v_xor_b32 %0, %7, %3\n\t"                                        \
          "v_bcnt_u32_b32 %1, %0, %1\n\t"                                   \
          "v_xor_b32 %0, %8, %4\n\t"                                        \
          "v_bcnt_u32_b32 %1, %0, %1\n\t"                                   \
          "v_xor_b32 %0, %9, %5\n\t"                                        \
          "v_bcnt_u32_b32 %1, %0, %1"                                       \
          : "=&v"(t_), "+v"(acc)                                            \
          : "v"((xv).x), "v"((xv).y), "v"((xv).z), "v"((xv).w),             \
            "s"((wv).x), "s"((wv).y), "s"((wv).z), "s"((wv).w)); }

// ---------------------------------------------------------------------------
// Binary GEMM layer. 128 rows x 128 cols per 256-thread block.
// Thread = rows {lane, lane+64}; wave = 32 cols (wave-uniform).
// X in LDS (pitch-18 u64); W + thresholds via scalar loads.
// MAC loop pinned with inline asm (see R6 post-mortem: compiler allocated
// 24 VGPRs and inflated VALU 2.6x when left to its own devices).
__global__ void __launch_bounds__(256)
gemm_bin_kernel(const u64* __restrict__ Xin, const u64* __restrict__ Wp,
                const int2* __restrict__ th, u64* __restrict__ Xout) {
    __shared__ u64 Xs[128][18];      // slots 0..15 used, pitch 144 B

    const int tid = threadIdx.x;
    const int bc = blockIdx.x & 7;    // col block (8 x 128 cols)
    const int br = blockIdx.x >> 3;   // row block
    const int r0 = br * 128;

    // stage X: 2048 u64, coalesced per strip
#pragma unroll
    for (int k = 0; k < 8; ++k) {
        int f = tid + k * 256;
        int row = f & 127;
        int wq = f >> 7;
        Xs[row][wq] = Xin[(size_t)wq * BATCH + r0 + row];
    }
    __syncthreads();

    const int lane = tid & 63;
    const int w = __builtin_amdgcn_readfirstlane(tid >> 6);   // wave id, SGPR
    const int cbase = bc * 128 + w * 32;                      // scalar

    const uint4* xrowA = (const uint4*)&Xs[lane][0];
    const uint4* xrowB = (const uint4*)&Xs[lane + 64][0];

    unsigned int bitsA = 0, bitsB = 0;

#pragma unroll 1
    for (int jc = 0; jc < 4; ++jc) {
        int accA[8], accB[8];
#pragma unroll
        for (int u = 0; u < 8; ++u) { accA[u] = 0; accB[u] = 0; }

#pragma unroll
        for (int sp = 0; sp < 4; ++sp) {
            uint4 xa0 = xrowA[sp * 2], xa1 = xrowA[sp * 2 + 1];
            uint4 xb0 = xrowB[sp * 2], xb1 = xrowB[sp * 2 + 1];
#pragma unroll
            for (int u = 0; u < 8; ++u) {
                const uint4* wrow = (const uint4*)(Wp + (size_t)(cbase + jc * 8 + u) * KW);
                uint4 wv0 = wrow[sp * 2];          // scalar loads (uniform addr)
                uint4 wv1 = wrow[sp * 2 + 1];
                MACQ(accA[u], xa0, wv0);
                MACQ(accA[u], xa1, wv1);
                MACQ(accB[u], xb0, wv0);
                MACQ(accB[u], xb1, wv1);
            }
        }
#pragma unroll
        for (int u = 0; u < 8; ++u) {
            int2 t = th[cbase + jc * 8 + u];
            int hA = 1024 - 2 * accA[u];
            int hB = 1024 - 2 * accB[u];
            unsigned int ba = t.y ? (hA <= t.x) : (hA >= t.x);
            unsigned int bb = t.y ? (hB <= t.x) : (hB >= t.x);
            bitsA |= ba << (jc * 8 + u);
            bitsB |= bb << (jc * 8 + u);
        }
    }

    // store: output strips as u32 halves; wq = cbase>>6, half = (cbase>>5)&1
    const int wq = cbase >> 6;
    const int half = (cbase >> 5) & 1;
    unsigned int* out32 = (unsigned int*)Xout;
    out32[(size_t)wq * 2 * BATCH + (r0 + lane) * 2 + half] = bitsA;
    out32[(size_t)wq * 2 * BATCH + (r0 + lane + 64) * 2 + half] = bitsB;
}

// ---------------------------------------------------------------------------
// Final 1024 -> 10 binary matmul + TensorNorm. X3 column-major strips.
__global__ void __launch_bounds__(256) final_layer_kernel(
    const u64* __restrict__ X3, const u64* __restrict__ W4p,
    const float* __restrict__ tw, const float* __restrict__ tb,
    const float* __restrict__ tm, const float* __restrict__ tv,
    float* __restrict__ out) {
    __shared__ u64 Wl[NCLS * KW];
    if (threadIdx.x < NCLS * KW) Wl[threadIdx.x] = W4p[threadIdx.x];
    __syncthreads();

    int row = blockIdx.x * 256 + threadIdx.x;
    u64 xr[KW];
#pragma unroll
    for (int wq = 0; wq < KW; ++wq) xr[wq] = X3[(size_t)wq * BATCH + row];

    double sc = (double)tw[0] / sqrt((double)tv[0] + 1e-4);
    double off = (double)tb[0] - (double)tm[0] * sc;

#pragma unroll
    for (int c = 0; c < NCLS; ++c) {
        int p = 0;
#pragma unroll
        for (int wq = 0; wq < KW; ++wq)
            p += __builtin_popcountll(xr[wq] ^ Wl[c * KW + wq]);
        int h = 1024 - 2 * p;
        out[(size_t)row * NCLS + c] = (float)((double)h * sc + off);
    }
}

// ---------------------------------------------------------------------------
extern "C" void kernel_launch(void* const* d_in, const int* in_sizes, int n_in,
                              void* d_out, int out_size, void* d_ws, size_t ws_size,
                              hipStream_t stream) {
    const float* x  = (const float*)d_in[0];
    const float* W1 = (const float*)d_in[1];
    const float* W2 = (const float*)d_in[2];
    const float* W3 = (const float*)d_in[3];
    const float* W4 = (const float*)d_in[4];
    const float* g1 = (const float*)d_in[5];
    const float* b1 = (const float*)d_in[6];
    const float* m1 = (const float*)d_in[7];
    const float* v1 = (const float*)d_in[8];
    const float* g2 = (const float*)d_in[9];
    const float* b2 = (const float*)d_in[10];
    const float* m2 = (const float*)d_in[11];
    const float* v2 = (const float*)d_in[12];
    const float* g3 = (const float*)d_in[13];
    const float* b3 = (const float*)d_in[14];
    const float* m3 = (const float*)d_in[15];
    const float* v3 = (const float*)d_in[16];
    const float* tw = (const float*)d_in[17];
    const float* tb = (const float*)d_in[18];
    const float* tm = (const float*)d_in[19];
    const float* tv = (const float*)d_in[20];

    char* ws = (char*)d_ws;
    u64* XA  = (u64*)(ws + OFF_XA);
    u64* XB  = (u64*)(ws + OFF_XB);
    u64* Wp1 = (u64*)(ws + OFF_WP1);
    u64* Wp2 = (u64*)(ws + OFF_WP2);
    u64* Wp3 = (u64*)(ws + OFF_WP3);
    u64* Wp4 = (u64*)(ws + OFF_WP4);
    int2* TH = (int2*)(ws + OFF_TH);

    int nprep = NB_X + 3 * NB_W + NB_W4 + NB_TH;
    prep_kernel<<<nprep, 256, 0, stream>>>(x, W1, W2, W3, W4,
                                           g1, b1, m1, v1, g2, b2, m2, v2,
                                           g3, b3, m3, v3,
                                           XA, Wp1, Wp2, Wp3, Wp4, TH);

    gemm_bin_kernel<<<1024, 256, 0, stream>>>(XA, Wp1, TH,        XB);
    gemm_bin_kernel<<<1024, 256, 0, stream>>>(XB, Wp2, TH + 1024, XA);
    gemm_bin_kernel<<<1024, 256, 0, stream>>>(XA, Wp3, TH + 2048, XB);

    final_layer_kernel<<<64, 256, 0, stream>>>(XB, Wp4, tw, tb, tm, tv,
                                               (float*)d_out);
}